// Round 2
// baseline (217.315 us; speedup 1.0000x reference)
//
#include <hip/hip_runtime.h>
#include <hip/hip_bf16.h>

// out[b, i*E + j] = x[b, i] * W[i, j]
// B=8192, L=100, E=64 -> 209.7 MB fp32 output, pure write-streaming bound.
//
// Round-5 = round-4 resubmit (container flake, no kernel verdict).
//
// Structure: DECOUPLE the x loads from the store stream. Round-3 interleaved
// one dependent scalar x-load per unroll-4 store group; loads and stores
// share vmcnt, so every wave's store stream stalled ~600-900 cy per group
// waiting on L3/HBM-latency x reads (the 210 MB write stream thrashes x out
// of the 4 MB/XCD L2). Kernel ran ~79 us (~2.8 TB/s) vs the harness fill's
// 6.6 TB/s on the same buffer.
//
// Now: each thread preloads ALL 32 x-scalars it will ever need (one per
// batch slice) as a burst of 32 independent loads into registers (static
// indices -> VGPRs), then runs a pure store loop structurally identical to
// the fill kernel. Stores are nontemporal so the output stream doesn't
// evict the 3.3 MB x table from L2.
//
// Grid: x-dim 5 blocks x 320 threads cover all 1600 vec4 columns;
//       y-dim 256 slices of the batch -> 32 stores/thread.

#define LENGTH 100
#define EMBED 64
#define BATCH 8192
#define V4_PER_ROW (LENGTH * EMBED / 4)   // 1600
#define TPB 320                            // 5 waves; 5 blocks cover 1600 cols
#define BSLICES 256                        // batch slices
#define ITERS (BATCH / BSLICES)            // 32

typedef float vfloat4 __attribute__((ext_vector_type(4)));

__global__ __launch_bounds__(TPB) void chemical_embedding_kernel(
    const float* __restrict__ x,
    const float* __restrict__ W,
    float* __restrict__ out)
{
    const int r = blockIdx.x * TPB + threadIdx.x;   // vec4 column, [0,1600)
    const int i = r >> 4;                            // L index (E/4 = 16 vec4/i)

    // Loop-invariant: this thread's W fragment, loaded once.
    const vfloat4 w = reinterpret_cast<const vfloat4*>(W)[r];

    const int b0 = blockIdx.y;                       // starting batch row
    const float* __restrict__ xp = x + b0 * LENGTH + i;

    // ---- Phase 1: burst-load every x scalar this thread will need. ----
    // 32 independent loads, all in flight at once; static indices so s[]
    // lives in registers (no scratch).
    float s[ITERS];
#pragma unroll
    for (int it = 0; it < ITERS; ++it)
        s[it] = xp[it * (BSLICES * LENGTH)];

    // ---- Phase 2: pure store stream (fill-kernel-shaped). ----
    vfloat4* __restrict__ op =
        reinterpret_cast<vfloat4*>(out) + (size_t)b0 * V4_PER_ROW + r;
    const int ostep = BSLICES * V4_PER_ROW;          // out bump per slice

#pragma unroll
    for (int it = 0; it < ITERS; ++it) {
        const vfloat4 v = s[it] * w;                 // 4 muls
        __builtin_nontemporal_store(v, op);          // coalesced 16B store, nt
        op += ostep;
    }
}

extern "C" void kernel_launch(void* const* d_in, const int* in_sizes, int n_in,
                              void* d_out, int out_size, void* d_ws, size_t ws_size,
                              hipStream_t stream) {
    const float* x = (const float*)d_in[0];
    const float* W = (const float*)d_in[1];
    float* out = (float*)d_out;

    dim3 grid(V4_PER_ROW / TPB, BSLICES);            // (5, 256) = 1280 blocks
    chemical_embedding_kernel<<<grid, TPB, 0, stream>>>(x, W, out);
}